// Round 7
// baseline (1172.462 us; speedup 1.0000x reference)
//
#include <hip/hip_runtime.h>

#define N_NODES 100000
#define N_EDGES 1600000
#define DIM 128
#define NLAYERS 3
#define NGRAPHS 512
#define BN_EPS 1e-5f

#define SCHUNK 512                                  // nodes per scan block
#define SBLOCKS ((N_NODES + SCHUNK - 1) / SCHUNK)   // 196

#define WPL 5120     // shorts per W plane [128][40]
#define WCH 10240    // shorts per (phase,kc) chunk (hi+lo)
#define LSTRIDE 81920  // shorts per layer (2 phases * 4 kc * WCH)

typedef __attribute__((ext_vector_type(8))) short short8;
typedef __attribute__((ext_vector_type(4))) float f32x4;

// bf16 helpers (raw ushort bits; RNE convert)
__device__ __forceinline__ unsigned f2b(float f) {
  unsigned u = __float_as_uint(f);
  return (u + 0x7FFFu + ((u >> 16) & 1u)) >> 16;
}
__device__ __forceinline__ float b2f(unsigned hw) {
  return __uint_as_float(hw << 16);
}

// ---------------- CSR build ----------------
__global__ __launch_bounds__(256) void hist_kernel(const int* __restrict__ dst,
                                                   int* __restrict__ deg) {
  for (int e = blockIdx.x * blockDim.x + threadIdx.x; e < N_EDGES;
       e += gridDim.x * blockDim.x)
    atomicAdd(&deg[dst[e]], 1);
}

__global__ __launch_bounds__(256) void partial_kernel(const int* __restrict__ deg,
                                                      int* __restrict__ bsum) {
  __shared__ int red[256];
  const int t = threadIdx.x;
  const int i0 = blockIdx.x * SCHUNK + 2 * t;
  int s = 0;
  if (i0 + 1 < N_NODES) {
    const int2 v = *(const int2*)(deg + i0);
    s = v.x + v.y;
  } else if (i0 < N_NODES) {
    s = deg[i0];
  }
  red[t] = s;
  __syncthreads();
  for (int off = 128; off > 0; off >>= 1) {
    if (t < off) red[t] += red[t + off];
    __syncthreads();
  }
  if (t == 0) bsum[blockIdx.x] = red[0];
}

__global__ __launch_bounds__(256) void bscan_kernel(const int* __restrict__ bsum,
                                                    int* __restrict__ boff,
                                                    int* __restrict__ row_ptr) {
  __shared__ int s[256];
  const int t = threadIdx.x;
  const int v = (t < SBLOCKS) ? bsum[t] : 0;
  s[t] = v;
  __syncthreads();
  for (int off = 1; off < 256; off <<= 1) {
    int u = (t >= off) ? s[t - off] : 0;
    __syncthreads();
    s[t] += u;
    __syncthreads();
  }
  if (t < SBLOCKS) boff[t] = s[t] - v;  // exclusive
  if (t == SBLOCKS - 1) row_ptr[N_NODES] = s[t];
}

__global__ __launch_bounds__(256) void emit_kernel(const int* __restrict__ deg,
                                                   const int* __restrict__ boff,
                                                   int* __restrict__ row_ptr,
                                                   int* __restrict__ cursor) {
  __shared__ int s[256];
  const int t = threadIdx.x;
  const int i0 = blockIdx.x * SCHUNK + 2 * t;
  int d0 = 0, d1 = 0;
  if (i0 + 1 < N_NODES) {
    const int2 v = *(const int2*)(deg + i0);
    d0 = v.x; d1 = v.y;
  } else if (i0 < N_NODES) {
    d0 = deg[i0];
  }
  const int pair = d0 + d1;
  s[t] = pair;
  __syncthreads();
  for (int off = 1; off < 256; off <<= 1) {
    int u = (t >= off) ? s[t - off] : 0;
    __syncthreads();
    s[t] += u;
    __syncthreads();
  }
  const int base = boff[blockIdx.x] + s[t] - pair;
  if (i0 + 1 < N_NODES) {
    const int2 rp = make_int2(base, base + d0);
    *(int2*)(row_ptr + i0) = rp;
    *(int2*)(cursor + i0) = rp;
  } else if (i0 < N_NODES) {
    row_ptr[i0] = base;
    cursor[i0] = base;
  }
}

__global__ __launch_bounds__(256) void fill_kernel(const int* __restrict__ src,
                                                   const int* __restrict__ dst,
                                                   int* __restrict__ cursor,
                                                   int* __restrict__ col) {
  for (int e = blockIdx.x * blockDim.x + threadIdx.x; e < N_EDGES;
       e += gridDim.x * blockDim.x) {
    const int d = dst[e];
    const int pos = atomicAdd(&cursor[d], 1);
    col[pos] = src[e];
  }
}

// ---------------- weights: transpose + split-bf16 + pad (once per call) ----------------
// wsplit[(l*2+p)*4+kc] = chunk of [2 planes][128 n][40 kpad]; plane0 = hi, plane1 = lo
__global__ __launch_bounds__(256) void wcvt_kernel(const float* __restrict__ W1,
                                                   const float* __restrict__ W2,
                                                   ushort* __restrict__ wsplit) {
  const int id = blockIdx.x * 256 + threadIdx.x;  // 3*2*4*32*128 = 98304
  const int n = id & 127;
  const int kk = (id >> 7) & 31;
  const int kc = (id >> 12) & 3;
  const int p = (id >> 14) & 1;
  const int l = id >> 15;
  const float* src = p ? W2 : W1;
  const float v = src[(size_t)l * 16384 + (kc * 32 + kk) * 128 + n];
  const unsigned hi = f2b(v);
  const unsigned lo = f2b(v - b2f(hi));
  ushort* dst = wsplit + (size_t)((l * 2 + p) * 4 + kc) * WCH + n * 40 + kk;
  dst[0] = (ushort)hi;
  dst[WPL] = (ushort)lo;
}

// ---------------- aggregation (f32): agg[i] = z[i] + sum_{j in N(i)} z[j] ----------------
__global__ __launch_bounds__(256) void agg_kernel(const float* __restrict__ zin,
                                                  int zstride,
                                                  const int* __restrict__ row_ptr,
                                                  const int* __restrict__ col,
                                                  float* __restrict__ agg) {
  const int w = (blockIdx.x * 256 + threadIdx.x) >> 6;  // one wave per node
  const int lane = threadIdx.x & 63;
  if (w >= N_NODES) return;
  const int start = row_ptr[w];
  const int end = row_ptr[w + 1];

  float2 acc = ((const float2*)(zin + (size_t)w * zstride))[lane];  // + z[i]
  int j = start;
  for (; j + 8 <= end; j += 8) {
    const int c0 = col[j], c1 = col[j + 1], c2 = col[j + 2], c3 = col[j + 3];
    const int c4 = col[j + 4], c5 = col[j + 5], c6 = col[j + 6], c7 = col[j + 7];
    const float2 v0 = ((const float2*)(zin + (size_t)c0 * zstride))[lane];
    const float2 v1 = ((const float2*)(zin + (size_t)c1 * zstride))[lane];
    const float2 v2 = ((const float2*)(zin + (size_t)c2 * zstride))[lane];
    const float2 v3 = ((const float2*)(zin + (size_t)c3 * zstride))[lane];
    const float2 v4 = ((const float2*)(zin + (size_t)c4 * zstride))[lane];
    const float2 v5 = ((const float2*)(zin + (size_t)c5 * zstride))[lane];
    const float2 v6 = ((const float2*)(zin + (size_t)c6 * zstride))[lane];
    const float2 v7 = ((const float2*)(zin + (size_t)c7 * zstride))[lane];
    acc.x += ((v0.x + v1.x) + (v2.x + v3.x)) + ((v4.x + v5.x) + (v6.x + v7.x));
    acc.y += ((v0.y + v1.y) + (v2.y + v3.y)) + ((v4.y + v5.y) + (v6.y + v7.y));
  }
  for (; j + 4 <= end; j += 4) {
    const int c0 = col[j], c1 = col[j + 1], c2 = col[j + 2], c3 = col[j + 3];
    const float2 v0 = ((const float2*)(zin + (size_t)c0 * zstride))[lane];
    const float2 v1 = ((const float2*)(zin + (size_t)c1 * zstride))[lane];
    const float2 v2 = ((const float2*)(zin + (size_t)c2 * zstride))[lane];
    const float2 v3 = ((const float2*)(zin + (size_t)c3 * zstride))[lane];
    acc.x += (v0.x + v1.x) + (v2.x + v3.x);
    acc.y += (v0.y + v1.y) + (v2.y + v3.y);
  }
  for (; j < end; ++j) {
    const int c = col[j];
    const float2 v = ((const float2*)(zin + (size_t)c * zstride))[lane];
    acc.x += v.x;
    acc.y += v.y;
  }
  ((float2*)(agg + (size_t)w * DIM))[lane] = acc;
}

// ---------------- split-bf16 MFMA MLP (fp32-grade accuracy) ----------------
// block = 256 thr = 4 waves; 64 rows; wave wv owns rows [16wv,16wv+16)
// A-frag: lane l -> row l&15, k = 8*(l>>4)+j ; B-frag: lane l -> col l&15, same k
// D: lane l reg r -> row (l>>4)*4+r, col l&15   (layout verified by R5 output-0 pass)
// C = Ah@Bh + Al@Bh + Ah@Bl  (Al@Bl ~2^-18, dropped)
__global__ __launch_bounds__(256) void mlp_kernel(
    const float* __restrict__ X,      // agg [N][128] f32
    const ushort* __restrict__ Wsp,   // this layer's 8 chunks: [(p*4+kc)][2][128][40]
    const float* __restrict__ b1,
    const float* __restrict__ b2,
    float* __restrict__ out,          // d_out, row stride 384
    int lcol,
    float* __restrict__ bnsum) {      // [256]: sum | sumsq
  __shared__ __align__(16) ushort smem[2 * 64 * 136 + WCH];  // 55296 B
  ushort* Xh = smem;                 // [64][136] bf16 hi (X, then H)
  ushort* Xl = smem + 64 * 136;      // [64][136] bf16 lo
  ushort* Wc = smem + 2 * 64 * 136;  // [2][128][40] staged W chunk
  float* red = (float*)smem;         // epilogue overlay (16x128 f32 = 8KB)

  const int tid = threadIdx.x;
  const int l = tid & 63, wv = tid >> 6;
  const int lr = l & 15, lg = l >> 4;
  const int n0 = blockIdx.x * 64;

  // stage X tile, splitting f32 -> hi/lo bf16
  for (int i = tid; i < 64 * 32; i += 256) {
    const int row = i >> 5, c4 = (i & 31) * 4;
    float4 v = make_float4(0.f, 0.f, 0.f, 0.f);
    if (n0 + row < N_NODES) v = *(const float4*)(X + (size_t)(n0 + row) * 128 + c4);
    ushort4 hi, lo;
    hi.x = (ushort)f2b(v.x); lo.x = (ushort)f2b(v.x - b2f(hi.x));
    hi.y = (ushort)f2b(v.y); lo.y = (ushort)f2b(v.y - b2f(hi.y));
    hi.z = (ushort)f2b(v.z); lo.z = (ushort)f2b(v.z - b2f(hi.z));
    hi.w = (ushort)f2b(v.w); lo.w = (ushort)f2b(v.w - b2f(hi.w));
    *(ushort4*)(Xh + row * 136 + c4) = hi;
    *(ushort4*)(Xl + row * 136 + c4) = lo;
  }

  f32x4 acc[8];
#pragma unroll
  for (int p = 0; p < 2; ++p) {
#pragma unroll
    for (int nt = 0; nt < 8; ++nt) acc[nt] = {0.f, 0.f, 0.f, 0.f};
#pragma unroll
    for (int kc = 0; kc < 4; ++kc) {
      __syncthreads();  // prior chunk reads (and X staging / h1 writes) done
      {  // stage W chunk (hi+lo planes, contiguous 20480 B)
        const uint4* wsrc = (const uint4*)(Wsp + (size_t)(p * 4 + kc) * WCH);
        for (int i = tid; i < WCH / 8; i += 256) ((uint4*)Wc)[i] = wsrc[i];
      }
      __syncthreads();
      const short8 ah = *(const short8*)(Xh + (wv * 16 + lr) * 136 + kc * 32 + lg * 8);
      const short8 al = *(const short8*)(Xl + (wv * 16 + lr) * 136 + kc * 32 + lg * 8);
#pragma unroll
      for (int nt = 0; nt < 8; ++nt) {
        const short8 bh = *(const short8*)(Wc + (nt * 16 + lr) * 40 + lg * 8);
        const short8 bl = *(const short8*)(Wc + WPL + (nt * 16 + lr) * 40 + lg * 8);
        acc[nt] = __builtin_amdgcn_mfma_f32_16x16x32_bf16(ah, bh, acc[nt], 0, 0, 0);
        acc[nt] = __builtin_amdgcn_mfma_f32_16x16x32_bf16(al, bh, acc[nt], 0, 0, 0);
        acc[nt] = __builtin_amdgcn_mfma_f32_16x16x32_bf16(ah, bl, acc[nt], 0, 0, 0);
      }
    }
    if (p == 0) {
      // h1 = relu(acc + b1) -> Xh/Xl (own rows only; cross-wave safe)
      __syncthreads();  // all waves done reading X frags of this phase
      float b1v[8];
#pragma unroll
      for (int nt = 0; nt < 8; ++nt) b1v[nt] = b1[nt * 16 + lr];
#pragma unroll
      for (int nt = 0; nt < 8; ++nt) {
#pragma unroll
        for (int r = 0; r < 4; ++r) {
          const float h = fmaxf(acc[nt][r] + b1v[nt], 0.f);
          const unsigned hi = f2b(h);
          const unsigned lo = f2b(h - b2f(hi));
          Xh[(wv * 16 + lg * 4 + r) * 136 + nt * 16 + lr] = (ushort)hi;
          Xl[(wv * 16 + lg * 4 + r) * 136 + nt * 16 + lr] = (ushort)lo;
        }
      }
    }
  }

  // epilogue: relu(acc + b2) -> out, BN partials
  float s[8], q2[8];
  {
    float b2v[8];
#pragma unroll
    for (int nt = 0; nt < 8; ++nt) b2v[nt] = b2[nt * 16 + lr];
#pragma unroll
    for (int nt = 0; nt < 8; ++nt) { s[nt] = 0.f; q2[nt] = 0.f; }
#pragma unroll
    for (int nt = 0; nt < 8; ++nt) {
#pragma unroll
      for (int r = 0; r < 4; ++r) {
        const int n = n0 + wv * 16 + lg * 4 + r;
        const float h = fmaxf(acc[nt][r] + b2v[nt], 0.f);
        if (n < N_NODES) {
          out[(size_t)n * (NLAYERS * DIM) + lcol + nt * 16 + lr] = h;
          s[nt] += h;
          q2[nt] += h * h;
        }
      }
    }
  }
  __syncthreads();  // all LDS reads done; red overlays Xh

  const int rg = tid >> 4, cb = tid & 15;
#pragma unroll
  for (int nt = 0; nt < 8; ++nt) red[rg * 128 + nt * 16 + cb] = s[nt];
  __syncthreads();
  if (tid < 128) {
    float t = 0.f;
#pragma unroll
    for (int g = 0; g < 16; ++g) t += red[g * 128 + tid];
    unsafeAtomicAdd(&bnsum[tid], t);
  }
  __syncthreads();
#pragma unroll
  for (int nt = 0; nt < 8; ++nt) red[rg * 128 + nt * 16 + cb] = q2[nt];
  __syncthreads();
  if (tid < 128) {
    float t = 0.f;
#pragma unroll
    for (int g = 0; g < 16; ++g) t += red[g * 128 + tid];
    unsafeAtomicAdd(&bnsum[128 + tid], t);
  }
}

// ---------------- BN finalize + normalize ----------------
__global__ __launch_bounds__(128) void bn_finalize_kernel(
    const float* __restrict__ bnsum, const float* __restrict__ gamma,
    const float* __restrict__ beta, float* __restrict__ bnfin) {
  const int c = threadIdx.x;
  const float inv_n = 1.f / (float)N_NODES;
  const float mu = bnsum[c] * inv_n;
  const float var = bnsum[128 + c] * inv_n - mu * mu;
  const float inv = rsqrtf(var + BN_EPS);
  const float sc = gamma[c] * inv;
  bnfin[c] = sc;
  bnfin[128 + c] = beta[c] - mu * sc;
}

__global__ __launch_bounds__(256) void bn_norm_kernel(float* __restrict__ zcol,
                                                      const float* __restrict__ bnfin) {
  const int idx = blockIdx.x * 256 + threadIdx.x;
  if (idx >= N_NODES * 32) return;
  const int n = idx >> 5, c4 = idx & 31;
  const float4 sc = ((const float4*)bnfin)[c4];
  const float4 sh = ((const float4*)(bnfin + 128))[c4];
  float4* p = (float4*)(zcol + (size_t)n * (NLAYERS * DIM)) + c4;
  float4 v = *p;
  v.x = fmaf(v.x, sc.x, sh.x);
  v.y = fmaf(v.y, sc.y, sh.y);
  v.z = fmaf(v.z, sc.z, sh.z);
  v.w = fmaf(v.w, sc.w, sh.w);
  *p = v;
}

// ---------------- graph pooling (batch is sorted) ----------------
__global__ __launch_bounds__(128) void pool_kernel(const float* __restrict__ zout,
                                                   const int* __restrict__ batch,
                                                   float* __restrict__ gout) {
  const int g = blockIdx.x / 3;
  const int chunk = blockIdx.x % 3;
  const int c = chunk * 128 + threadIdx.x;
  int lo = 0, hi = N_NODES;
  while (lo < hi) {
    const int m = (lo + hi) >> 1;
    if (batch[m] < g) lo = m + 1; else hi = m;
  }
  int lo2 = lo, hi2 = N_NODES;
  while (lo2 < hi2) {
    const int m = (lo2 + hi2) >> 1;
    if (batch[m] < g + 1) lo2 = m + 1; else hi2 = m;
  }
  float acc = 0.f;
  for (int n = lo; n < lo2; ++n) acc += zout[(size_t)n * (NLAYERS * DIM) + c];
  gout[(size_t)g * (NLAYERS * DIM) + c] = acc;
}

// ---------------- launch ----------------
extern "C" void kernel_launch(void* const* d_in, const int* in_sizes, int n_in,
                              void* d_out, int out_size, void* d_ws, size_t ws_size,
                              hipStream_t stream) {
  const float* x = (const float*)d_in[0];
  const int* ei = (const int*)d_in[1];
  const int* src = ei;
  const int* dst = ei + N_EDGES;
  const int* batch = (const int*)d_in[2];
  const float* W1 = (const float*)d_in[3];
  const float* b1 = (const float*)d_in[4];
  const float* W2 = (const float*)d_in[5];
  const float* b2 = (const float*)d_in[6];
  const float* gamma = (const float*)d_in[7];
  const float* beta = (const float*)d_in[8];
  float* out = (float*)d_out;
  float* gout = out + (size_t)N_NODES * NLAYERS * DIM;

  char* ws = (char*)d_ws;
  size_t off = 0;
  auto alloc = [&](size_t bytes) -> void* {
    off = (off + 511) & ~(size_t)511;
    void* p = ws + off;
    off += bytes;
    return p;
  };
  int* row_ptr = (int*)alloc((N_NODES + 1) * sizeof(int));
  int* cursor = (int*)alloc(N_NODES * sizeof(int));
  int* deg = (int*)alloc(N_NODES * sizeof(int));
  int* col = (int*)alloc(N_EDGES * sizeof(int));
  int* bsum = (int*)alloc(SBLOCKS * sizeof(int));
  int* boff = (int*)alloc(SBLOCKS * sizeof(int));
  float* agg = (float*)alloc((size_t)N_NODES * DIM * sizeof(float));
  ushort* wsplit = (ushort*)alloc((size_t)NLAYERS * LSTRIDE * sizeof(ushort));
  float* bnsum = (float*)alloc(NLAYERS * 256 * sizeof(float));
  float* bnfin = (float*)alloc(NLAYERS * 256 * sizeof(float));

  hipMemsetAsync(deg, 0, N_NODES * sizeof(int), stream);
  hipMemsetAsync(bnsum, 0, NLAYERS * 256 * sizeof(float), stream);

  hist_kernel<<<2048, 256, 0, stream>>>(dst, deg);
  partial_kernel<<<SBLOCKS, 256, 0, stream>>>(deg, bsum);
  bscan_kernel<<<1, 256, 0, stream>>>(bsum, boff, row_ptr);
  emit_kernel<<<SBLOCKS, 256, 0, stream>>>(deg, boff, row_ptr, cursor);
  fill_kernel<<<2048, 256, 0, stream>>>(src, dst, cursor, col);
  wcvt_kernel<<<384, 256, 0, stream>>>(W1, W2, wsplit);

  for (int l = 0; l < NLAYERS; ++l) {
    const float* zin = (l == 0) ? x : (out + (size_t)(l - 1) * DIM);
    const int zstride = (l == 0) ? DIM : NLAYERS * DIM;
    agg_kernel<<<(N_NODES * 64 + 255) / 256, 256, 0, stream>>>(zin, zstride,
                                                               row_ptr, col, agg);
    mlp_kernel<<<(N_NODES + 63) / 64, 256, 0, stream>>>(
        agg, wsplit + (size_t)l * LSTRIDE, b1 + (size_t)l * DIM,
        b2 + (size_t)l * DIM, out, l * DIM, bnsum + l * 256);
    bn_finalize_kernel<<<1, 128, 0, stream>>>(bnsum + l * 256, gamma + l * DIM,
                                              beta + l * DIM, bnfin + l * 256);
    bn_norm_kernel<<<(N_NODES * 32 + 255) / 256, 256, 0, stream>>>(
        out + (size_t)l * DIM, bnfin + l * 256);
  }
  pool_kernel<<<NGRAPHS * 3, 128, 0, stream>>>(out, batch, gout);
}

// Round 10
// 1025.637 us; speedup vs baseline: 1.1432x; 1.1432x over previous
//
#include <hip/hip_runtime.h>

#define N_NODES 100000
#define N_EDGES 1600000
#define DIM 128
#define NLAYERS 3
#define NGRAPHS 512
#define BN_EPS 1e-5f

#define SCHUNK 512                                  // nodes per scan block
#define SBLOCKS ((N_NODES + SCHUNK - 1) / SCHUNK)   // 196

#define WPL 5120       // shorts per W plane [128][40]
#define WCH 10240      // shorts per (phase,kc) chunk (hi+lo)
#define LSTRIDE 81920  // shorts per layer (2 phases * 4 kc * WCH)

typedef __attribute__((ext_vector_type(8))) short short8;
typedef __attribute__((ext_vector_type(4))) float f32x4;

// bf16 helpers (raw ushort bits; RNE convert)
__device__ __forceinline__ unsigned f2b(float f) {
  unsigned u = __float_as_uint(f);
  return (u + 0x7FFFu + ((u >> 16) & 1u)) >> 16;
}
__device__ __forceinline__ float b2f(unsigned hw) {
  return __uint_as_float(hw << 16);
}

// ---------------- CSR build ----------------
__global__ __launch_bounds__(256) void hist_kernel(const int* __restrict__ dst,
                                                   int* __restrict__ deg) {
  for (int e = blockIdx.x * blockDim.x + threadIdx.x; e < N_EDGES;
       e += gridDim.x * blockDim.x)
    atomicAdd(&deg[dst[e]], 1);
}

__global__ __launch_bounds__(256) void partial_kernel(const int* __restrict__ deg,
                                                      int* __restrict__ bsum) {
  __shared__ int red[256];
  const int t = threadIdx.x;
  const int i0 = blockIdx.x * SCHUNK + 2 * t;
  int s = 0;
  if (i0 + 1 < N_NODES) {
    const int2 v = *(const int2*)(deg + i0);
    s = v.x + v.y;
  } else if (i0 < N_NODES) {
    s = deg[i0];
  }
  red[t] = s;
  __syncthreads();
  for (int off = 128; off > 0; off >>= 1) {
    if (t < off) red[t] += red[t + off];
    __syncthreads();
  }
  if (t == 0) bsum[blockIdx.x] = red[0];
}

__global__ __launch_bounds__(256) void bscan_kernel(const int* __restrict__ bsum,
                                                    int* __restrict__ boff,
                                                    int* __restrict__ row_ptr) {
  __shared__ int s[256];
  const int t = threadIdx.x;
  const int v = (t < SBLOCKS) ? bsum[t] : 0;
  s[t] = v;
  __syncthreads();
  for (int off = 1; off < 256; off <<= 1) {
    int u = (t >= off) ? s[t - off] : 0;
    __syncthreads();
    s[t] += u;
    __syncthreads();
  }
  if (t < SBLOCKS) boff[t] = s[t] - v;  // exclusive
  if (t == SBLOCKS - 1) row_ptr[N_NODES] = s[t];
}

__global__ __launch_bounds__(256) void emit_kernel(const int* __restrict__ deg,
                                                   const int* __restrict__ boff,
                                                   int* __restrict__ row_ptr,
                                                   int* __restrict__ cursor) {
  __shared__ int s[256];
  const int t = threadIdx.x;
  const int i0 = blockIdx.x * SCHUNK + 2 * t;
  int d0 = 0, d1 = 0;
  if (i0 + 1 < N_NODES) {
    const int2 v = *(const int2*)(deg + i0);
    d0 = v.x; d1 = v.y;
  } else if (i0 < N_NODES) {
    d0 = deg[i0];
  }
  const int pair = d0 + d1;
  s[t] = pair;
  __syncthreads();
  for (int off = 1; off < 256; off <<= 1) {
    int u = (t >= off) ? s[t - off] : 0;
    __syncthreads();
    s[t] += u;
    __syncthreads();
  }
  const int base = boff[blockIdx.x] + s[t] - pair;
  if (i0 + 1 < N_NODES) {
    const int2 rp = make_int2(base, base + d0);
    *(int2*)(row_ptr + i0) = rp;
    *(int2*)(cursor + i0) = rp;
  } else if (i0 < N_NODES) {
    row_ptr[i0] = base;
    cursor[i0] = base;
  }
}

__global__ __launch_bounds__(256) void fill_kernel(const int* __restrict__ src,
                                                   const int* __restrict__ dst,
                                                   int* __restrict__ cursor,
                                                   int* __restrict__ col) {
  for (int e = blockIdx.x * blockDim.x + threadIdx.x; e < N_EDGES;
       e += gridDim.x * blockDim.x) {
    const int d = dst[e];
    const int pos = atomicAdd(&cursor[d], 1);
    col[pos] = src[e];
  }
}

// ---------------- x -> bf16 shadow (once per call) ----------------
__global__ __launch_bounds__(256) void xcvt_kernel(const float* __restrict__ x,
                                                   ushort* __restrict__ zb) {
  const int i = blockIdx.x * 256 + threadIdx.x;  // exactly N*DIM/8 threads
  const float4 a = ((const float4*)x)[2 * i];
  const float4 b = ((const float4*)x)[2 * i + 1];
  uint4 o;
  o.x = (f2b(a.y) << 16) | f2b(a.x);
  o.y = (f2b(a.w) << 16) | f2b(a.z);
  o.z = (f2b(b.y) << 16) | f2b(b.x);
  o.w = (f2b(b.w) << 16) | f2b(b.z);
  ((uint4*)zb)[i] = o;
}

// ---------------- weights: transpose + split-bf16 + pad (once per call) ----------------
// wsplit[(l*2+p)*4+kc] = chunk of [2 planes][128 n][40 kpad]; plane0 = hi, plane1 = lo
__global__ __launch_bounds__(256) void wcvt_kernel(const float* __restrict__ W1,
                                                   const float* __restrict__ W2,
                                                   ushort* __restrict__ wsplit) {
  const int id = blockIdx.x * 256 + threadIdx.x;  // 3*2*4*32*128 = 98304
  const int n = id & 127;
  const int kk = (id >> 7) & 31;
  const int kc = (id >> 12) & 3;
  const int p = (id >> 14) & 1;
  const int l = id >> 15;
  const float* src = p ? W2 : W1;
  const float v = src[(size_t)l * 16384 + (kc * 32 + kk) * 128 + n];
  const unsigned hi = f2b(v);
  const unsigned lo = f2b(v - b2f(hi));
  ushort* dst = wsplit + (size_t)((l * 2 + p) * 4 + kc) * WCH + n * 40 + kk;
  dst[0] = (ushort)hi;
  dst[WPL] = (ushort)lo;
}

// ---- aggregation: bf16 gather, f32 accumulate, hi/lo bf16 planes out ----
__global__ __launch_bounds__(256) void agg_kernel(const ushort* __restrict__ zb,
                                                  const int* __restrict__ row_ptr,
                                                  const int* __restrict__ col,
                                                  ushort* __restrict__ aggh,
                                                  ushort* __restrict__ aggl) {
  const int w = (blockIdx.x * 256 + threadIdx.x) >> 6;  // one wave per node
  const int lane = threadIdx.x & 63;
  if (w >= N_NODES) return;
  const int start = row_ptr[w];
  const int end = row_ptr[w + 1];

  const unsigned us = ((const unsigned*)(zb + (size_t)w * 128))[lane];  // self
  float ax = b2f(us & 0xFFFFu), ay = b2f(us >> 16);
  int j = start;
  for (; j + 8 <= end; j += 8) {
    const int c0 = col[j], c1 = col[j + 1], c2 = col[j + 2], c3 = col[j + 3];
    const int c4 = col[j + 4], c5 = col[j + 5], c6 = col[j + 6], c7 = col[j + 7];
    const unsigned u0 = ((const unsigned*)(zb + (size_t)c0 * 128))[lane];
    const unsigned u1 = ((const unsigned*)(zb + (size_t)c1 * 128))[lane];
    const unsigned u2 = ((const unsigned*)(zb + (size_t)c2 * 128))[lane];
    const unsigned u3 = ((const unsigned*)(zb + (size_t)c3 * 128))[lane];
    const unsigned u4 = ((const unsigned*)(zb + (size_t)c4 * 128))[lane];
    const unsigned u5 = ((const unsigned*)(zb + (size_t)c5 * 128))[lane];
    const unsigned u6 = ((const unsigned*)(zb + (size_t)c6 * 128))[lane];
    const unsigned u7 = ((const unsigned*)(zb + (size_t)c7 * 128))[lane];
    ax += ((b2f(u0 & 0xFFFFu) + b2f(u1 & 0xFFFFu)) + (b2f(u2 & 0xFFFFu) + b2f(u3 & 0xFFFFu))) +
          ((b2f(u4 & 0xFFFFu) + b2f(u5 & 0xFFFFu)) + (b2f(u6 & 0xFFFFu) + b2f(u7 & 0xFFFFu)));
    ay += ((b2f(u0 >> 16) + b2f(u1 >> 16)) + (b2f(u2 >> 16) + b2f(u3 >> 16))) +
          ((b2f(u4 >> 16) + b2f(u5 >> 16)) + (b2f(u6 >> 16) + b2f(u7 >> 16)));
  }
  for (; j + 4 <= end; j += 4) {
    const int c0 = col[j], c1 = col[j + 1], c2 = col[j + 2], c3 = col[j + 3];
    const unsigned u0 = ((const unsigned*)(zb + (size_t)c0 * 128))[lane];
    const unsigned u1 = ((const unsigned*)(zb + (size_t)c1 * 128))[lane];
    const unsigned u2 = ((const unsigned*)(zb + (size_t)c2 * 128))[lane];
    const unsigned u3 = ((const unsigned*)(zb + (size_t)c3 * 128))[lane];
    ax += (b2f(u0 & 0xFFFFu) + b2f(u1 & 0xFFFFu)) + (b2f(u2 & 0xFFFFu) + b2f(u3 & 0xFFFFu));
    ay += (b2f(u0 >> 16) + b2f(u1 >> 16)) + (b2f(u2 >> 16) + b2f(u3 >> 16));
  }
  for (; j < end; ++j) {
    const unsigned uc = ((const unsigned*)(zb + (size_t)col[j] * 128))[lane];
    ax += b2f(uc & 0xFFFFu);
    ay += b2f(uc >> 16);
  }
  const unsigned hx = f2b(ax), hy = f2b(ay);
  const unsigned lx = f2b(ax - b2f(hx)), ly = f2b(ay - b2f(hy));
  ((unsigned*)(aggh + (size_t)w * 128))[lane] = (hy << 16) | hx;
  ((unsigned*)(aggl + (size_t)w * 128))[lane] = (ly << 16) | lx;
}

// ---------------- split-bf16 MFMA MLP (fp32-grade accuracy) ----------------
// block = 256 thr = 4 waves; 64 rows; wave wv owns rows [16wv,16wv+16)
// A-frag: lane l -> row l&15, k = 8*(l>>4)+j ; B-frag: lane l -> col l&15, same k
// D: lane l reg r -> row (l>>4)*4+r, col l&15   (layout verified, R5 output-0 pass)
// C = Ah@Bh + Al@Bh + Ah@Bl  (Al@Bl ~2^-18, dropped)
__global__ __launch_bounds__(256) void mlp_kernel(
    const ushort* __restrict__ Xhp,   // aggh [N][128] bf16 hi plane
    const ushort* __restrict__ Xlp,   // aggl [N][128] bf16 lo plane
    const ushort* __restrict__ Wsp,   // this layer's 8 chunks: [(p*4+kc)][2][128][40]
    const float* __restrict__ b1,
    const float* __restrict__ b2,
    float* __restrict__ out,          // d_out, row stride 384
    int lcol,
    float* __restrict__ bnsum) {      // [256]: sum | sumsq
  __shared__ __align__(16) ushort smem[2 * 64 * 136 + WCH];  // 55296 B
  ushort* Xh = smem;                 // [64][136] bf16 hi (X, then H)
  ushort* Xl = smem + 64 * 136;      // [64][136] bf16 lo
  ushort* Wc = smem + 2 * 64 * 136;  // [2][128][40] staged W chunk
  float* red = (float*)smem;         // epilogue overlay (16x128 f32 = 8KB)

  const int tid = threadIdx.x;
  const int l = tid & 63, wv = tid >> 6;
  const int lr = l & 15, lg = l >> 4;
  const int n0 = blockIdx.x * 64;

  // stage X tile (hi/lo planes, direct int4 copies)
  for (int i = tid; i < 64 * 16; i += 256) {
    const int row = i >> 4, ch = i & 15;
    int4 vh = make_int4(0, 0, 0, 0), vl = vh;
    if (n0 + row < N_NODES) {
      vh = *(const int4*)(Xhp + (size_t)(n0 + row) * 128 + ch * 8);
      vl = *(const int4*)(Xlp + (size_t)(n0 + row) * 128 + ch * 8);
    }
    *(int4*)(Xh + row * 136 + ch * 8) = vh;
    *(int4*)(Xl + row * 136 + ch * 8) = vl;
  }

  f32x4 acc[8];
#pragma unroll
  for (int p = 0; p < 2; ++p) {
#pragma unroll
    for (int nt = 0; nt < 8; ++nt) acc[nt] = {0.f, 0.f, 0.f, 0.f};
#pragma unroll
    for (int kc = 0; kc < 4; ++kc) {
      __syncthreads();  // prior chunk reads (and X staging / h1 writes) done
      {  // stage W chunk (hi+lo planes, contiguous 20480 B)
        const uint4* wsrc = (const uint4*)(Wsp + (size_t)(p * 4 + kc) * WCH);
        for (int i = tid; i < WCH / 8; i += 256) ((uint4*)Wc)[i] = wsrc[i];
      }
      __syncthreads();
      const short8 ah = *(const short8*)(Xh + (wv * 16 + lr) * 136 + kc * 32 + lg * 8);
      const short8 al = *(const short8*)(Xl + (wv * 16 + lr) * 136 + kc * 32 + lg * 8);
#pragma unroll
      for (int nt = 0; nt < 8; ++nt) {
        const short8 bh = *(const short8*)(Wc + (nt * 16 + lr) * 40 + lg * 8);
        const short8 bl = *(const short8*)(Wc + WPL + (nt * 16 + lr) * 40 + lg * 8);
        acc[nt] = __builtin_amdgcn_mfma_f32_16x16x32_bf16(ah, bh, acc[nt], 0, 0, 0);
        acc[nt] = __builtin_amdgcn_mfma_f32_16x16x32_bf16(al, bh, acc[nt], 0, 0, 0);
        acc[nt] = __builtin_amdgcn_mfma_f32_16x16x32_bf16(ah, bl, acc[nt], 0, 0, 0);
      }
    }
    if (p == 0) {
      // h1 = relu(acc + b1) -> Xh/Xl (own rows only; cross-wave safe)
      __syncthreads();  // all waves done reading X frags of this phase
      float b1v[8];
#pragma unroll
      for (int nt = 0; nt < 8; ++nt) b1v[nt] = b1[nt * 16 + lr];
#pragma unroll
      for (int nt = 0; nt < 8; ++nt) {
#pragma unroll
        for (int r = 0; r < 4; ++r) {
          const float h = fmaxf(acc[nt][r] + b1v[nt], 0.f);
          const unsigned hi = f2b(h);
          const unsigned lo = f2b(h - b2f(hi));
          Xh[(wv * 16 + lg * 4 + r) * 136 + nt * 16 + lr] = (ushort)hi;
          Xl[(wv * 16 + lg * 4 + r) * 136 + nt * 16 + lr] = (ushort)lo;
        }
      }
    }
  }

  // epilogue: relu(acc + b2) -> out, BN partials
  float s[8], q2[8];
  {
    float b2v[8];
#pragma unroll
    for (int nt = 0; nt < 8; ++nt) b2v[nt] = b2[nt * 16 + lr];
#pragma unroll
    for (int nt = 0; nt < 8; ++nt) { s[nt] = 0.f; q2[nt] = 0.f; }
#pragma unroll
    for (int nt = 0; nt < 8; ++nt) {
#pragma unroll
      for (int r = 0; r < 4; ++r) {
        const int n = n0 + wv * 16 + lg * 4 + r;
        const float h = fmaxf(acc[nt][r] + b2v[nt], 0.f);
        if (n < N_NODES) {
          out[(size_t)n * (NLAYERS * DIM) + lcol + nt * 16 + lr] = h;
          s[nt] += h;
          q2[nt] += h * h;
        }
      }
    }
  }
  __syncthreads();  // all LDS reads done; red overlays Xh

  const int rg = tid >> 4, cb = tid & 15;
#pragma unroll
  for (int nt = 0; nt < 8; ++nt) red[rg * 128 + nt * 16 + cb] = s[nt];
  __syncthreads();
  if (tid < 128) {
    float t = 0.f;
#pragma unroll
    for (int g = 0; g < 16; ++g) t += red[g * 128 + tid];
    unsafeAtomicAdd(&bnsum[tid], t);
  }
  __syncthreads();
#pragma unroll
  for (int nt = 0; nt < 8; ++nt) red[rg * 128 + nt * 16 + cb] = q2[nt];
  __syncthreads();
  if (tid < 128) {
    float t = 0.f;
#pragma unroll
    for (int g = 0; g < 16; ++g) t += red[g * 128 + tid];
    unsafeAtomicAdd(&bnsum[128 + tid], t);
  }
}

// ---------------- BN finalize + normalize ----------------
__global__ __launch_bounds__(128) void bn_finalize_kernel(
    const float* __restrict__ bnsum, const float* __restrict__ gamma,
    const float* __restrict__ beta, float* __restrict__ bnfin) {
  const int c = threadIdx.x;
  const float inv_n = 1.f / (float)N_NODES;
  const float mu = bnsum[c] * inv_n;
  const float var = bnsum[128 + c] * inv_n - mu * mu;
  const float inv = rsqrtf(var + BN_EPS);
  const float sc = gamma[c] * inv;
  bnfin[c] = sc;
  bnfin[128 + c] = beta[c] - mu * sc;
}

// normalize f32 column block in-place; optionally emit bf16 z for next gather
__global__ __launch_bounds__(256) void bn_norm_kernel(float* __restrict__ zcol,
                                                      const float* __restrict__ bnfin,
                                                      ushort* __restrict__ zb) {
  const int idx = blockIdx.x * 256 + threadIdx.x;
  if (idx >= N_NODES * 32) return;
  const int n = idx >> 5, c4 = idx & 31;
  const float4 sc = ((const float4*)bnfin)[c4];
  const float4 sh = ((const float4*)(bnfin + 128))[c4];
  float4* p = (float4*)(zcol + (size_t)n * (NLAYERS * DIM)) + c4;
  float4 v = *p;
  v.x = fmaf(v.x, sc.x, sh.x);
  v.y = fmaf(v.y, sc.y, sh.y);
  v.z = fmaf(v.z, sc.z, sh.z);
  v.w = fmaf(v.w, sc.w, sh.w);
  *p = v;
  if (zb) {
    uint2 o;
    o.x = (f2b(v.y) << 16) | f2b(v.x);
    o.y = (f2b(v.w) << 16) | f2b(v.z);
    *(uint2*)(zb + (size_t)n * 128 + c4 * 4) = o;
  }
}

// ---------------- graph pooling (batch is sorted) ----------------
__global__ __launch_bounds__(128) void pool_kernel(const float* __restrict__ zout,
                                                   const int* __restrict__ batch,
                                                   float* __restrict__ gout) {
  const int g = blockIdx.x / 3;
  const int chunk = blockIdx.x % 3;
  const int c = chunk * 128 + threadIdx.x;
  int lo = 0, hi = N_NODES;
  while (lo < hi) {
    const int m = (lo + hi) >> 1;
    if (batch[m] < g) lo = m + 1; else hi = m;
  }
  int lo2 = lo, hi2 = N_NODES;
  while (lo2 < hi2) {
    const int m = (lo2 + hi2) >> 1;
    if (batch[m] < g + 1) lo2 = m + 1; else hi2 = m;
  }
  float acc = 0.f;
  for (int n = lo; n < lo2; ++n) acc += zout[(size_t)n * (NLAYERS * DIM) + c];
  gout[(size_t)g * (NLAYERS * DIM) + c] = acc;
}

// ---------------- launch ----------------
extern "C" void kernel_launch(void* const* d_in, const int* in_sizes, int n_in,
                              void* d_out, int out_size, void* d_ws, size_t ws_size,
                              hipStream_t stream) {
  const float* x = (const float*)d_in[0];
  const int* ei = (const int*)d_in[1];
  const int* src = ei;
  const int* dst = ei + N_EDGES;
  const int* batch = (const int*)d_in[2];
  const float* W1 = (const float*)d_in[3];
  const float* b1 = (const float*)d_in[4];
  const float* W2 = (const float*)d_in[5];
  const float* b2 = (const float*)d_in[6];
  const float* gamma = (const float*)d_in[7];
  const float* beta = (const float*)d_in[8];
  float* out = (float*)d_out;
  float* gout = out + (size_t)N_NODES * NLAYERS * DIM;

  char* ws = (char*)d_ws;
  size_t off = 0;
  auto alloc = [&](size_t bytes) -> void* {
    off = (off + 511) & ~(size_t)511;
    void* p = ws + off;
    off += bytes;
    return p;
  };
  int* row_ptr = (int*)alloc((N_NODES + 1) * sizeof(int));
  int* cursor = (int*)alloc(N_NODES * sizeof(int));
  int* deg = (int*)alloc(N_NODES * sizeof(int));
  int* col = (int*)alloc(N_EDGES * sizeof(int));
  int* bsum = (int*)alloc(SBLOCKS * sizeof(int));
  int* boff = (int*)alloc(SBLOCKS * sizeof(int));
  ushort* zb = (ushort*)alloc((size_t)N_NODES * 128 * sizeof(ushort));
  ushort* aggh = (ushort*)alloc((size_t)N_NODES * 128 * sizeof(ushort));
  ushort* aggl = (ushort*)alloc((size_t)N_NODES * 128 * sizeof(ushort));
  ushort* wsplit = (ushort*)alloc((size_t)NLAYERS * LSTRIDE * sizeof(ushort));
  float* bnsum = (float*)alloc(NLAYERS * 256 * sizeof(float));
  float* bnfin = (float*)alloc(NLAYERS * 256 * sizeof(float));

  hipMemsetAsync(deg, 0, N_NODES * sizeof(int), stream);
  hipMemsetAsync(bnsum, 0, NLAYERS * 256 * sizeof(float), stream);

  hist_kernel<<<2048, 256, 0, stream>>>(dst, deg);
  partial_kernel<<<SBLOCKS, 256, 0, stream>>>(deg, bsum);
  bscan_kernel<<<1, 256, 0, stream>>>(bsum, boff, row_ptr);
  emit_kernel<<<SBLOCKS, 256, 0, stream>>>(deg, boff, row_ptr, cursor);
  fill_kernel<<<2048, 256, 0, stream>>>(src, dst, cursor, col);
  xcvt_kernel<<<(N_NODES * DIM / 8) / 256, 256, 0, stream>>>(x, zb);
  wcvt_kernel<<<384, 256, 0, stream>>>(W1, W2, wsplit);

  for (int l = 0; l < NLAYERS; ++l) {
    agg_kernel<<<(N_NODES * 64 + 255) / 256, 256, 0, stream>>>(zb, row_ptr, col,
                                                               aggh, aggl);
    mlp_kernel<<<(N_NODES + 63) / 64, 256, 0, stream>>>(
        aggh, aggl, wsplit + (size_t)l * LSTRIDE, b1 + (size_t)l * DIM,
        b2 + (size_t)l * DIM, out, l * DIM, bnsum + l * 256);
    bn_finalize_kernel<<<1, 128, 0, stream>>>(bnsum + l * 256, gamma + l * DIM,
                                              beta + l * DIM, bnfin + l * 256);
    bn_norm_kernel<<<(N_NODES * 32 + 255) / 256, 256, 0, stream>>>(
        out + (size_t)l * DIM, bnfin + l * 256, (l < NLAYERS - 1) ? zb : nullptr);
  }
  pool_kernel<<<NGRAPHS * 3, 128, 0, stream>>>(out, batch, gout);
}

// Round 11
// 966.913 us; speedup vs baseline: 1.2126x; 1.0607x over previous
//
#include <hip/hip_runtime.h>

#define N_NODES 100000
#define N_EDGES 1600000
#define DIM 128
#define NLAYERS 3
#define NGRAPHS 512
#define BN_EPS 1e-5f

#define SCHUNK 512                                  // nodes per scan block
#define SBLOCKS ((N_NODES + SCHUNK - 1) / SCHUNK)   // 196

#define WPL 5120       // shorts per W plane [128][40]
#define WCH 10240      // shorts per (phase,kc) chunk (hi+lo)
#define LSTRIDE 81920  // shorts per layer (2 phases * 4 kc * WCH)

#define NRANGE 8                       // dst ranges (XCD-aligned via blockIdx&7)
#define RNODES (N_NODES / NRANGE)      // 12500 nodes per range

typedef __attribute__((ext_vector_type(8))) short short8;
typedef __attribute__((ext_vector_type(4))) float f32x4;

// bf16 helpers (raw ushort bits; RNE convert)
__device__ __forceinline__ unsigned f2b(float f) {
  unsigned u = __float_as_uint(f);
  return (u + 0x7FFFu + ((u >> 16) & 1u)) >> 16;
}
__device__ __forceinline__ float b2f(unsigned hw) {
  return __uint_as_float(hw << 16);
}

// ---------------- CSR build ----------------
__global__ __launch_bounds__(256) void hist_kernel(const int* __restrict__ dst,
                                                   int* __restrict__ deg) {
  for (int e = blockIdx.x * blockDim.x + threadIdx.x; e < N_EDGES;
       e += gridDim.x * blockDim.x)
    atomicAdd(&deg[dst[e]], 1);
}

__global__ __launch_bounds__(256) void partial_kernel(const int* __restrict__ deg,
                                                      int* __restrict__ bsum) {
  __shared__ int red[256];
  const int t = threadIdx.x;
  const int i0 = blockIdx.x * SCHUNK + 2 * t;
  int s = 0;
  if (i0 + 1 < N_NODES) {
    const int2 v = *(const int2*)(deg + i0);
    s = v.x + v.y;
  } else if (i0 < N_NODES) {
    s = deg[i0];
  }
  red[t] = s;
  __syncthreads();
  for (int off = 128; off > 0; off >>= 1) {
    if (t < off) red[t] += red[t + off];
    __syncthreads();
  }
  if (t == 0) bsum[blockIdx.x] = red[0];
}

__global__ __launch_bounds__(256) void bscan_kernel(const int* __restrict__ bsum,
                                                    int* __restrict__ boff,
                                                    int* __restrict__ row_ptr) {
  __shared__ int s[256];
  const int t = threadIdx.x;
  const int v = (t < SBLOCKS) ? bsum[t] : 0;
  s[t] = v;
  __syncthreads();
  for (int off = 1; off < 256; off <<= 1) {
    int u = (t >= off) ? s[t - off] : 0;
    __syncthreads();
    s[t] += u;
    __syncthreads();
  }
  if (t < SBLOCKS) boff[t] = s[t] - v;  // exclusive
  if (t == SBLOCKS - 1) row_ptr[N_NODES] = s[t];
}

__global__ __launch_bounds__(256) void emit_kernel(const int* __restrict__ deg,
                                                   const int* __restrict__ boff,
                                                   int* __restrict__ row_ptr,
                                                   int* __restrict__ cursor) {
  __shared__ int s[256];
  const int t = threadIdx.x;
  const int i0 = blockIdx.x * SCHUNK + 2 * t;
  int d0 = 0, d1 = 0;
  if (i0 + 1 < N_NODES) {
    const int2 v = *(const int2*)(deg + i0);
    d0 = v.x; d1 = v.y;
  } else if (i0 < N_NODES) {
    d0 = deg[i0];
  }
  const int pair = d0 + d1;
  s[t] = pair;
  __syncthreads();
  for (int off = 1; off < 256; off <<= 1) {
    int u = (t >= off) ? s[t - off] : 0;
    __syncthreads();
    s[t] += u;
    __syncthreads();
  }
  const int base = boff[blockIdx.x] + s[t] - pair;
  if (i0 + 1 < N_NODES) {
    const int2 rp = make_int2(base, base + d0);
    *(int2*)(row_ptr + i0) = rp;
    *(int2*)(cursor + i0) = rp;
  } else if (i0 < N_NODES) {
    row_ptr[i0] = base;
    cursor[i0] = base;
  }
}

// dst-ranged fill: range r = blockIdx&7 (XCD-aligned under round-robin dispatch).
// Each range's col window (~800KB) + cursor slice (50KB) stay L2-resident on one
// XCD -> scattered stores coalesce in L2, write back once (kills 16x write-amp).
// Edge list re-read NRANGE times from L3 (cheap). Semantics identical.
__global__ __launch_bounds__(256) void fill_kernel(const int* __restrict__ src,
                                                   const int* __restrict__ dst,
                                                   int* __restrict__ cursor,
                                                   int* __restrict__ col) {
  const int r = blockIdx.x & (NRANGE - 1);
  const int lo = r * RNODES;
  const int hi = lo + RNODES;
  const int nb = gridDim.x >> 3;   // blocks per range group
  const int bi = blockIdx.x >> 3;  // index within range group
  for (int e = bi * 256 + threadIdx.x; e < N_EDGES; e += nb * 256) {
    const int d = dst[e];
    if (d >= lo && d < hi) {
      const int pos = atomicAdd(&cursor[d], 1);
      col[pos] = src[e];
    }
  }
}

// ---------------- x -> bf16 shadow (once per call) ----------------
__global__ __launch_bounds__(256) void xcvt_kernel(const float* __restrict__ x,
                                                   ushort* __restrict__ zb) {
  const int i = blockIdx.x * 256 + threadIdx.x;  // exactly N*DIM/8 threads
  const float4 a = ((const float4*)x)[2 * i];
  const float4 b = ((const float4*)x)[2 * i + 1];
  uint4 o;
  o.x = (f2b(a.y) << 16) | f2b(a.x);
  o.y = (f2b(a.w) << 16) | f2b(a.z);
  o.z = (f2b(b.y) << 16) | f2b(b.x);
  o.w = (f2b(b.w) << 16) | f2b(b.z);
  ((uint4*)zb)[i] = o;
}

// ---------------- weights: transpose + split-bf16 + pad (once per call) ----------------
// wsplit[(l*2+p)*4+kc] = chunk of [2 planes][128 n][40 kpad]; plane0 = hi, plane1 = lo
__global__ __launch_bounds__(256) void wcvt_kernel(const float* __restrict__ W1,
                                                   const float* __restrict__ W2,
                                                   ushort* __restrict__ wsplit) {
  const int id = blockIdx.x * 256 + threadIdx.x;  // 3*2*4*32*128 = 98304
  const int n = id & 127;
  const int kk = (id >> 7) & 31;
  const int kc = (id >> 12) & 3;
  const int p = (id >> 14) & 1;
  const int l = id >> 15;
  const float* src = p ? W2 : W1;
  const float v = src[(size_t)l * 16384 + (kc * 32 + kk) * 128 + n];
  const unsigned hi = f2b(v);
  const unsigned lo = f2b(v - b2f(hi));
  ushort* dst = wsplit + (size_t)((l * 2 + p) * 4 + kc) * WCH + n * 40 + kk;
  dst[0] = (ushort)hi;
  dst[WPL] = (ushort)lo;
}

// ---- aggregation: bf16 gather, f32 accumulate, hi/lo bf16 planes out ----
__global__ __launch_bounds__(256) void agg_kernel(const ushort* __restrict__ zb,
                                                  const int* __restrict__ row_ptr,
                                                  const int* __restrict__ col,
                                                  ushort* __restrict__ aggh,
                                                  ushort* __restrict__ aggl) {
  const int w = (blockIdx.x * 256 + threadIdx.x) >> 6;  // one wave per node
  const int lane = threadIdx.x & 63;
  if (w >= N_NODES) return;
  const int start = row_ptr[w];
  const int end = row_ptr[w + 1];

  const unsigned us = ((const unsigned*)(zb + (size_t)w * 128))[lane];  // self
  float ax = b2f(us & 0xFFFFu), ay = b2f(us >> 16);
  int j = start;
  for (; j + 8 <= end; j += 8) {
    const int c0 = col[j], c1 = col[j + 1], c2 = col[j + 2], c3 = col[j + 3];
    const int c4 = col[j + 4], c5 = col[j + 5], c6 = col[j + 6], c7 = col[j + 7];
    const unsigned u0 = ((const unsigned*)(zb + (size_t)c0 * 128))[lane];
    const unsigned u1 = ((const unsigned*)(zb + (size_t)c1 * 128))[lane];
    const unsigned u2 = ((const unsigned*)(zb + (size_t)c2 * 128))[lane];
    const unsigned u3 = ((const unsigned*)(zb + (size_t)c3 * 128))[lane];
    const unsigned u4 = ((const unsigned*)(zb + (size_t)c4 * 128))[lane];
    const unsigned u5 = ((const unsigned*)(zb + (size_t)c5 * 128))[lane];
    const unsigned u6 = ((const unsigned*)(zb + (size_t)c6 * 128))[lane];
    const unsigned u7 = ((const unsigned*)(zb + (size_t)c7 * 128))[lane];
    ax += ((b2f(u0 & 0xFFFFu) + b2f(u1 & 0xFFFFu)) + (b2f(u2 & 0xFFFFu) + b2f(u3 & 0xFFFFu))) +
          ((b2f(u4 & 0xFFFFu) + b2f(u5 & 0xFFFFu)) + (b2f(u6 & 0xFFFFu) + b2f(u7 & 0xFFFFu)));
    ay += ((b2f(u0 >> 16) + b2f(u1 >> 16)) + (b2f(u2 >> 16) + b2f(u3 >> 16))) +
          ((b2f(u4 >> 16) + b2f(u5 >> 16)) + (b2f(u6 >> 16) + b2f(u7 >> 16)));
  }
  for (; j + 4 <= end; j += 4) {
    const int c0 = col[j], c1 = col[j + 1], c2 = col[j + 2], c3 = col[j + 3];
    const unsigned u0 = ((const unsigned*)(zb + (size_t)c0 * 128))[lane];
    const unsigned u1 = ((const unsigned*)(zb + (size_t)c1 * 128))[lane];
    const unsigned u2 = ((const unsigned*)(zb + (size_t)c2 * 128))[lane];
    const unsigned u3 = ((const unsigned*)(zb + (size_t)c3 * 128))[lane];
    ax += (b2f(u0 & 0xFFFFu) + b2f(u1 & 0xFFFFu)) + (b2f(u2 & 0xFFFFu) + b2f(u3 & 0xFFFFu));
    ay += (b2f(u0 >> 16) + b2f(u1 >> 16)) + (b2f(u2 >> 16) + b2f(u3 >> 16));
  }
  for (; j < end; ++j) {
    const unsigned uc = ((const unsigned*)(zb + (size_t)col[j] * 128))[lane];
    ax += b2f(uc & 0xFFFFu);
    ay += b2f(uc >> 16);
  }
  const unsigned hx = f2b(ax), hy = f2b(ay);
  const unsigned lx = f2b(ax - b2f(hx)), ly = f2b(ay - b2f(hy));
  ((unsigned*)(aggh + (size_t)w * 128))[lane] = (hy << 16) | hx;
  ((unsigned*)(aggl + (size_t)w * 128))[lane] = (ly << 16) | lx;
}

// ---------------- split-bf16 MFMA MLP (fp32-grade accuracy) ----------------
// block = 256 thr = 4 waves; 64 rows; wave wv owns rows [16wv,16wv+16)
// A-frag: lane l -> row l&15, k = 8*(l>>4)+j ; B-frag: lane l -> col l&15, same k
// D: lane l reg r -> row (l>>4)*4+r, col l&15   (layout verified, R5 output-0 pass)
// C = Ah@Bh + Al@Bh + Ah@Bl  (Al@Bl ~2^-18, dropped)
__global__ __launch_bounds__(256) void mlp_kernel(
    const ushort* __restrict__ Xhp,   // aggh [N][128] bf16 hi plane
    const ushort* __restrict__ Xlp,   // aggl [N][128] bf16 lo plane
    const ushort* __restrict__ Wsp,   // this layer's 8 chunks: [(p*4+kc)][2][128][40]
    const float* __restrict__ b1,
    const float* __restrict__ b2,
    float* __restrict__ out,          // d_out, row stride 384
    int lcol,
    float* __restrict__ bnsum) {      // [256]: sum | sumsq
  __shared__ __align__(16) ushort smem[2 * 64 * 136 + WCH];  // 55296 B
  ushort* Xh = smem;                 // [64][136] bf16 hi (X, then H)
  ushort* Xl = smem + 64 * 136;      // [64][136] bf16 lo
  ushort* Wc = smem + 2 * 64 * 136;  // [2][128][40] staged W chunk
  float* red = (float*)smem;         // epilogue overlay (16x128 f32 = 8KB)

  const int tid = threadIdx.x;
  const int l = tid & 63, wv = tid >> 6;
  const int lr = l & 15, lg = l >> 4;
  const int n0 = blockIdx.x * 64;

  // stage X tile (hi/lo planes, direct int4 copies)
  for (int i = tid; i < 64 * 16; i += 256) {
    const int row = i >> 4, ch = i & 15;
    int4 vh = make_int4(0, 0, 0, 0), vl = vh;
    if (n0 + row < N_NODES) {
      vh = *(const int4*)(Xhp + (size_t)(n0 + row) * 128 + ch * 8);
      vl = *(const int4*)(Xlp + (size_t)(n0 + row) * 128 + ch * 8);
    }
    *(int4*)(Xh + row * 136 + ch * 8) = vh;
    *(int4*)(Xl + row * 136 + ch * 8) = vl;
  }

  f32x4 acc[8];
#pragma unroll
  for (int p = 0; p < 2; ++p) {
#pragma unroll
    for (int nt = 0; nt < 8; ++nt) acc[nt] = {0.f, 0.f, 0.f, 0.f};
#pragma unroll
    for (int kc = 0; kc < 4; ++kc) {
      __syncthreads();  // prior chunk reads (and X staging / h1 writes) done
      {  // stage W chunk (hi+lo planes, contiguous 20480 B)
        const uint4* wsrc = (const uint4*)(Wsp + (size_t)(p * 4 + kc) * WCH);
        for (int i = tid; i < WCH / 8; i += 256) ((uint4*)Wc)[i] = wsrc[i];
      }
      __syncthreads();
      const short8 ah = *(const short8*)(Xh + (wv * 16 + lr) * 136 + kc * 32 + lg * 8);
      const short8 al = *(const short8*)(Xl + (wv * 16 + lr) * 136 + kc * 32 + lg * 8);
#pragma unroll
      for (int nt = 0; nt < 8; ++nt) {
        const short8 bh = *(const short8*)(Wc + (nt * 16 + lr) * 40 + lg * 8);
        const short8 bl = *(const short8*)(Wc + WPL + (nt * 16 + lr) * 40 + lg * 8);
        acc[nt] = __builtin_amdgcn_mfma_f32_16x16x32_bf16(ah, bh, acc[nt], 0, 0, 0);
        acc[nt] = __builtin_amdgcn_mfma_f32_16x16x32_bf16(al, bh, acc[nt], 0, 0, 0);
        acc[nt] = __builtin_amdgcn_mfma_f32_16x16x32_bf16(ah, bl, acc[nt], 0, 0, 0);
      }
    }
    if (p == 0) {
      // h1 = relu(acc + b1) -> Xh/Xl (own rows only; cross-wave safe)
      __syncthreads();  // all waves done reading X frags of this phase
      float b1v[8];
#pragma unroll
      for (int nt = 0; nt < 8; ++nt) b1v[nt] = b1[nt * 16 + lr];
#pragma unroll
      for (int nt = 0; nt < 8; ++nt) {
#pragma unroll
        for (int r = 0; r < 4; ++r) {
          const float h = fmaxf(acc[nt][r] + b1v[nt], 0.f);
          const unsigned hi = f2b(h);
          const unsigned lo = f2b(h - b2f(hi));
          Xh[(wv * 16 + lg * 4 + r) * 136 + nt * 16 + lr] = (ushort)hi;
          Xl[(wv * 16 + lg * 4 + r) * 136 + nt * 16 + lr] = (ushort)lo;
        }
      }
    }
  }

  // epilogue: relu(acc + b2) -> out, BN partials
  float s[8], q2[8];
  {
    float b2v[8];
#pragma unroll
    for (int nt = 0; nt < 8; ++nt) b2v[nt] = b2[nt * 16 + lr];
#pragma unroll
    for (int nt = 0; nt < 8; ++nt) { s[nt] = 0.f; q2[nt] = 0.f; }
#pragma unroll
    for (int nt = 0; nt < 8; ++nt) {
#pragma unroll
      for (int r = 0; r < 4; ++r) {
        const int n = n0 + wv * 16 + lg * 4 + r;
        const float h = fmaxf(acc[nt][r] + b2v[nt], 0.f);
        if (n < N_NODES) {
          out[(size_t)n * (NLAYERS * DIM) + lcol + nt * 16 + lr] = h;
          s[nt] += h;
          q2[nt] += h * h;
        }
      }
    }
  }
  __syncthreads();  // all LDS reads done; red overlays Xh

  const int rg = tid >> 4, cb = tid & 15;
#pragma unroll
  for (int nt = 0; nt < 8; ++nt) red[rg * 128 + nt * 16 + cb] = s[nt];
  __syncthreads();
  if (tid < 128) {
    float t = 0.f;
#pragma unroll
    for (int g = 0; g < 16; ++g) t += red[g * 128 + tid];
    unsafeAtomicAdd(&bnsum[tid], t);
  }
  __syncthreads();
#pragma unroll
  for (int nt = 0; nt < 8; ++nt) red[rg * 128 + nt * 16 + cb] = q2[nt];
  __syncthreads();
  if (tid < 128) {
    float t = 0.f;
#pragma unroll
    for (int g = 0; g < 16; ++g) t += red[g * 128 + tid];
    unsafeAtomicAdd(&bnsum[128 + tid], t);
  }
}

// ---------------- BN finalize + normalize ----------------
__global__ __launch_bounds__(128) void bn_finalize_kernel(
    const float* __restrict__ bnsum, const float* __restrict__ gamma,
    const float* __restrict__ beta, float* __restrict__ bnfin) {
  const int c = threadIdx.x;
  const float inv_n = 1.f / (float)N_NODES;
  const float mu = bnsum[c] * inv_n;
  const float var = bnsum[128 + c] * inv_n - mu * mu;
  const float inv = rsqrtf(var + BN_EPS);
  const float sc = gamma[c] * inv;
  bnfin[c] = sc;
  bnfin[128 + c] = beta[c] - mu * sc;
}

// normalize f32 column block in-place; optionally emit bf16 z for next gather
__global__ __launch_bounds__(256) void bn_norm_kernel(float* __restrict__ zcol,
                                                      const float* __restrict__ bnfin,
                                                      ushort* __restrict__ zb) {
  const int idx = blockIdx.x * 256 + threadIdx.x;
  if (idx >= N_NODES * 32) return;
  const int n = idx >> 5, c4 = idx & 31;
  const float4 sc = ((const float4*)bnfin)[c4];
  const float4 sh = ((const float4*)(bnfin + 128))[c4];
  float4* p = (float4*)(zcol + (size_t)n * (NLAYERS * DIM)) + c4;
  float4 v = *p;
  v.x = fmaf(v.x, sc.x, sh.x);
  v.y = fmaf(v.y, sc.y, sh.y);
  v.z = fmaf(v.z, sc.z, sh.z);
  v.w = fmaf(v.w, sc.w, sh.w);
  *p = v;
  if (zb) {
    uint2 o;
    o.x = (f2b(v.y) << 16) | f2b(v.x);
    o.y = (f2b(v.w) << 16) | f2b(v.z);
    *(uint2*)(zb + (size_t)n * 128 + c4 * 4) = o;
  }
}

// ---------------- graph pooling (batch is sorted) ----------------
__global__ __launch_bounds__(128) void pool_kernel(const float* __restrict__ zout,
                                                   const int* __restrict__ batch,
                                                   float* __restrict__ gout) {
  const int g = blockIdx.x / 3;
  const int chunk = blockIdx.x % 3;
  const int c = chunk * 128 + threadIdx.x;
  int lo = 0, hi = N_NODES;
  while (lo < hi) {
    const int m = (lo + hi) >> 1;
    if (batch[m] < g) lo = m + 1; else hi = m;
  }
  int lo2 = lo, hi2 = N_NODES;
  while (lo2 < hi2) {
    const int m = (lo2 + hi2) >> 1;
    if (batch[m] < g + 1) lo2 = m + 1; else hi2 = m;
  }
  float acc = 0.f;
  for (int n = lo; n < lo2; ++n) acc += zout[(size_t)n * (NLAYERS * DIM) + c];
  gout[(size_t)g * (NLAYERS * DIM) + c] = acc;
}

// ---------------- launch ----------------
extern "C" void kernel_launch(void* const* d_in, const int* in_sizes, int n_in,
                              void* d_out, int out_size, void* d_ws, size_t ws_size,
                              hipStream_t stream) {
  const float* x = (const float*)d_in[0];
  const int* ei = (const int*)d_in[1];
  const int* src = ei;
  const int* dst = ei + N_EDGES;
  const int* batch = (const int*)d_in[2];
  const float* W1 = (const float*)d_in[3];
  const float* b1 = (const float*)d_in[4];
  const float* W2 = (const float*)d_in[5];
  const float* b2 = (const float*)d_in[6];
  const float* gamma = (const float*)d_in[7];
  const float* beta = (const float*)d_in[8];
  float* out = (float*)d_out;
  float* gout = out + (size_t)N_NODES * NLAYERS * DIM;

  char* ws = (char*)d_ws;
  size_t off = 0;
  auto alloc = [&](size_t bytes) -> void* {
    off = (off + 511) & ~(size_t)511;
    void* p = ws + off;
    off += bytes;
    return p;
  };
  int* row_ptr = (int*)alloc((N_NODES + 1) * sizeof(int));
  int* cursor = (int*)alloc(N_NODES * sizeof(int));
  int* deg = (int*)alloc(N_NODES * sizeof(int));
  int* col = (int*)alloc(N_EDGES * sizeof(int));
  int* bsum = (int*)alloc(SBLOCKS * sizeof(int));
  int* boff = (int*)alloc(SBLOCKS * sizeof(int));
  ushort* zb = (ushort*)alloc((size_t)N_NODES * 128 * sizeof(ushort));
  ushort* aggh = (ushort*)alloc((size_t)N_NODES * 128 * sizeof(ushort));
  ushort* aggl = (ushort*)alloc((size_t)N_NODES * 128 * sizeof(ushort));
  ushort* wsplit = (ushort*)alloc((size_t)NLAYERS * LSTRIDE * sizeof(ushort));
  float* bnsum = (float*)alloc(NLAYERS * 256 * sizeof(float));
  float* bnfin = (float*)alloc(NLAYERS * 256 * sizeof(float));

  hipMemsetAsync(deg, 0, N_NODES * sizeof(int), stream);
  hipMemsetAsync(bnsum, 0, NLAYERS * 256 * sizeof(float), stream);

  hist_kernel<<<2048, 256, 0, stream>>>(dst, deg);
  partial_kernel<<<SBLOCKS, 256, 0, stream>>>(deg, bsum);
  bscan_kernel<<<1, 256, 0, stream>>>(bsum, boff, row_ptr);
  emit_kernel<<<SBLOCKS, 256, 0, stream>>>(deg, boff, row_ptr, cursor);
  fill_kernel<<<2048, 256, 0, stream>>>(src, dst, cursor, col);
  xcvt_kernel<<<(N_NODES * DIM / 8) / 256, 256, 0, stream>>>(x, zb);
  wcvt_kernel<<<384, 256, 0, stream>>>(W1, W2, wsplit);

  for (int l = 0; l < NLAYERS; ++l) {
    agg_kernel<<<(N_NODES * 64 + 255) / 256, 256, 0, stream>>>(zb, row_ptr, col,
                                                               aggh, aggl);
    mlp_kernel<<<(N_NODES + 63) / 64, 256, 0, stream>>>(
        aggh, aggl, wsplit + (size_t)l * LSTRIDE, b1 + (size_t)l * DIM,
        b2 + (size_t)l * DIM, out, l * DIM, bnsum + l * 256);
    bn_finalize_kernel<<<1, 128, 0, stream>>>(bnsum + l * 256, gamma + l * DIM,
                                              beta + l * DIM, bnfin + l * 256);
    bn_norm_kernel<<<(N_NODES * 32 + 255) / 256, 256, 0, stream>>>(
        out + (size_t)l * DIM, bnfin + l * 256, (l < NLAYERS - 1) ? zb : nullptr);
  }
  pool_kernel<<<NGRAPHS * 3, 128, 0, stream>>>(out, batch, gout);
}